// Round 6
// baseline (341.878 us; speedup 1.0000x reference)
//
#include <hip/hip_runtime.h>
#include <math.h>

#define N_PTS   1000000
#define CI      10
#define C       64
#define NSEG    30000
#define BN_EPS  1e-3f

// ws layout (floats):
// [0:10)    colsum(inp)              (accumulator, zeroed)
// [10:65)   M = sum row*row^T, upper-tri i<=j row-major (55)  (zeroed)
// [128:192) a = rstd*gamma           (written by k_gstats blocks, identical values)
// [192:256) b = beta - mu*a
// [256:320) g_sum                    (accumulator, zeroed)
// [384:1024) W' = a*W  (64x10, row-major)
// ints at [1024:1024+NSEG): segment starts

using f32x4 = __attribute__((ext_vector_type(4))) float;
using s16x8 = __attribute__((ext_vector_type(8))) short;

__device__ inline short f2bf(float x) {           // RNE fp32 -> bf16 (weights)
    unsigned u = __float_as_uint(x);
    unsigned r = (u + 0x7fffu + ((u >> 16) & 1u)) >> 16;
    return (short)r;
}
__device__ inline unsigned pack_trunc(float lo, float hi) {  // 2x bf16 truncate
    return (__float_as_uint(hi) & 0xffff0000u) | (__float_as_uint(lo) >> 16);
}
__device__ inline float frcp(float x) { return __builtin_amdgcn_rcpf(x); }

// Kernel 1: colsum[10] + second-moment M[55] of raw inputs (BN stats from 65
// scalars since linear commutes with the point-sum). Fused: segment starts.
__global__ void __launch_bounds__(256) k_moments(const float* __restrict__ inp,
                                                 const int* __restrict__ idx,
                                                 float* __restrict__ ws,
                                                 int* __restrict__ starts) {
    const int tid = threadIdx.x;
    float v[65];
#pragma unroll
    for (int k = 0; k < 65; ++k) v[k] = 0.f;

    for (int p = blockIdx.x * blockDim.x + tid; p < N_PTS; p += gridDim.x * blockDim.x) {
        const float2* r2 = (const float2*)(inp + (size_t)p * CI);
        float2 a0 = r2[0], a1 = r2[1], a2 = r2[2], a3 = r2[3], a4 = r2[4];
        float r[CI] = {a0.x, a0.y, a1.x, a1.y, a2.x, a2.y, a3.x, a3.y, a4.x, a4.y};
#pragma unroll
        for (int i = 0; i < CI; ++i) v[i] += r[i];
        int kk = 10;
#pragma unroll
        for (int i = 0; i < CI; ++i)
#pragma unroll
            for (int j = i; j < CI; ++j) { v[kk] = fmaf(r[i], r[j], v[kk]); ++kk; }

        int iv = idx[p];
        if (p == 0) starts[0] = 0;
        else if (idx[p - 1] != iv) starts[iv] = p;
    }

#pragma unroll
    for (int k = 0; k < 65; ++k) {
#pragma unroll
        for (int off = 32; off >= 1; off >>= 1)
            v[k] += __shfl_xor(v[k], off, 64);
    }
    __shared__ float red[4 * 65];
    const int wv = tid >> 6, ln = tid & 63;
    if (ln == 0) {
#pragma unroll
        for (int k = 0; k < 65; ++k) red[wv * 65 + k] = v[k];
    }
    __syncthreads();
    if (tid < 65)
        atomicAdd(&ws[tid], red[tid] + red[65 + tid] + red[130 + tid] + red[195 + tid]);
}

// Kernel 2 (fused finalize + gstats): per-block BN finalize from the 65
// moments (identical in every block; also stored to ws for k_main), then
// g_sum[c] = sum_p relu(x'_pc + b_c) via MFMA linear, 16-pt batches,
// 62500 full batches. One-deep row prefetch.
__global__ void __launch_bounds__(256) k_gstats(const float* __restrict__ inp,
                                                const float* __restrict__ W,
                                                const float* __restrict__ gamma,
                                                const float* __restrict__ beta,
                                                float* __restrict__ ws) {
    const int tid  = threadIdx.x;
    const int wv   = tid >> 6;
    const int lane = tid & 63;
    const int m = lane & 15;
    const int q = lane >> 4;

    __shared__ float wp[C * CI];   // W' = a*W
    __shared__ float bsh[C];

    // ---- finalize (wave 0 computes; all blocks also write ws for k_main)
    if (tid < C) {
        const int c = tid;
        float w[CI];
#pragma unroll
        for (int i = 0; i < CI; ++i) w[i] = W[c * CI + i];
        const float inv_n = 1.f / (float)N_PTS;

        float mu = 0.f;
#pragma unroll
        for (int i = 0; i < CI; ++i) mu = fmaf(w[i], ws[i], mu);
        mu *= inv_n;

        float ex2 = 0.f;
        int kk = 10;
#pragma unroll
        for (int i = 0; i < CI; ++i)
#pragma unroll
            for (int j = i; j < CI; ++j) {
                float mm = ws[kk];
                float t = w[i] * w[j] * mm;
                ex2 += (i == j) ? t : 2.f * t;
                ++kk;
            }
        ex2 *= inv_n;

        float var = ex2 - mu * mu;
        float rstd = rsqrtf(var + BN_EPS);
        float a = rstd * gamma[c];
        float b = beta[c] - mu * a;
        bsh[c] = b;
        ws[128 + c] = a;
        ws[192 + c] = b;
#pragma unroll
        for (int i = 0; i < CI; ++i) {
            float wi = a * w[i];
            wp[c * CI + i] = wi;
            ws[384 + c * CI + i] = wi;
        }
    }
    __syncthreads();

    // B-frags of W' (K padded to 32): B[k=8q+j][n=16nt+m]
    s16x8 wfr[4];
#pragma unroll
    for (int nt = 0; nt < 4; ++nt) {
        s16x8 t;
#pragma unroll
        for (int j = 0; j < 8; ++j) {
            int k = 8 * q + j;
            t[j] = (k < CI) ? f2bf(wp[(nt * 16 + m) * CI + k]) : (short)0;
        }
        wfr[nt] = t;
    }
    float bb[4];
#pragma unroll
    for (int nt = 0; nt < 4; ++nt) bb[nt] = bsh[nt * 16 + m];

    const int wid = blockIdx.x * 4 + wv;
    const int nw  = gridDim.x * 4;
    const int NB  = N_PTS / 16;          // 62500

    float2 P0, P1, P2, P3;
    auto loadrows = [&](int pb) {
        const float* row = inp + (size_t)(pb + m) * CI;
        if (q == 0) {
            P0 = *(const float2*)(row);     P1 = *(const float2*)(row + 2);
            P2 = *(const float2*)(row + 4); P3 = *(const float2*)(row + 6);
        } else if (q == 1) {
            P0 = *(const float2*)(row + 8);
        }
    };
    P0 = P1 = P2 = P3 = make_float2(0.f, 0.f);

    float sm[4] = {0.f, 0.f, 0.f, 0.f};
    const f32x4 zero = {0.f, 0.f, 0.f, 0.f};

    if (wid < NB) loadrows(wid * 16);
    for (int b = wid; b < NB; b += nw) {
        float2 L0 = P0, L1 = P1, L2 = P2, L3 = P3;
        if (b + nw < NB) loadrows((b + nw) * 16);

        union { s16x8 v; unsigned u[4]; } t;
        t.v = s16x8{0, 0, 0, 0, 0, 0, 0, 0};
        if (q < 2) t.u[0] = pack_trunc(L0.x, L0.y);
        if (q == 0) {
            t.u[1] = pack_trunc(L1.x, L1.y);
            t.u[2] = pack_trunc(L2.x, L2.y);
            t.u[3] = pack_trunc(L3.x, L3.y);
        }

        f32x4 xt[4];
#pragma unroll
        for (int nt = 0; nt < 4; ++nt) {
            xt[nt] = __builtin_amdgcn_mfma_f32_16x16x32_bf16(t.v, wfr[nt], zero, 0, 0, 0);
#pragma unroll
            for (int r = 0; r < 4; ++r)
                sm[nt] += fmaxf(xt[nt][r] + bb[nt], 0.f);
        }
    }

#pragma unroll
    for (int nt = 0; nt < 4; ++nt) {
        sm[nt] += __shfl_xor(sm[nt], 16, 64);
        sm[nt] += __shfl_xor(sm[nt], 32, 64);
    }
    float S = sm[0];
    if (q == 1) S = sm[1];
    if (q == 2) S = sm[2];
    if (q == 3) S = sm[3];

    __shared__ float red[4 * 64];
    red[wv * 64 + lane] = S;              // lane == channel
    __syncthreads();
    if (tid < 64)
        atomicAdd(&ws[256 + tid], red[tid] + red[64 + tid] + red[128 + tid] + red[192 + tid]);
}

// Kernel 3 (fused xg + main): per-block xg = pw2 @ relu(dw2*g) via MFMA
// (broadcast A-row, C-row 0), then one wave per 2 contiguous segments,
// streaming 16-pt batches across the boundary with segmented sum/max.
#define LD 68
#define SEGW 2
__global__ void __launch_bounds__(128) k_main(const float* __restrict__ inp,
                                              const float* __restrict__ dw1,
                                              const float* __restrict__ pw1,
                                              const float* __restrict__ dw2,
                                              const float* __restrict__ pw2,
                                              const float* __restrict__ ws,
                                              const int* __restrict__ starts,
                                              float* __restrict__ out) {
    const int tid  = threadIdx.x;
    const int wv   = tid >> 6;
    const int lane = tid & 63;
    const int m = lane & 15;
    const int q = lane >> 4;
    const f32x4 zero = {0.f, 0.f, 0.f, 0.f};

    // B-frags of W' (K padded to 32)
    s16x8 wfr[4];
#pragma unroll
    for (int nt = 0; nt < 4; ++nt) {
        s16x8 t;
#pragma unroll
        for (int j = 0; j < 8; ++j) {
            int k = 8 * q + j;
            t[j] = (k < CI) ? f2bf(ws[384 + (nt * 16 + m) * CI + k]) : (short)0;
        }
        wfr[nt] = t;
    }
    // B-frags of pw1
    s16x8 bfr[4][2];
#pragma unroll
    for (int nt = 0; nt < 4; ++nt)
#pragma unroll
        for (int kc = 0; kc < 2; ++kc) {
            const float* src = pw1 + (nt * 16 + m) * C + kc * 32 + q * 8;
            float4 p0 = *(const float4*)src;
            float4 p1 = *(const float4*)(src + 4);
            s16x8 t;
            t[0] = f2bf(p0.x); t[1] = f2bf(p0.y); t[2] = f2bf(p0.z); t[3] = f2bf(p0.w);
            t[4] = f2bf(p1.x); t[5] = f2bf(p1.y); t[6] = f2bf(p1.z); t[7] = f2bf(p1.w);
            bfr[nt][kc] = t;
        }

    float bb[4], d1v[4], xgv[4];
#pragma unroll
    for (int nt = 0; nt < 4; ++nt) {
        bb[nt]  = ws[192 + nt * 16 + m];
        d1v[nt] = dw1[nt * 16 + m];
    }

    // ---- fused xg: A-row t[k] = relu(dw2[k] * g[k]) broadcast to all 16 rows
    {
        const float inv_n = 1.f / (float)N_PTS;
        s16x8 axg[2];
#pragma unroll
        for (int kc = 0; kc < 2; ++kc) {
            union { s16x8 v; unsigned u[4]; } t;
#pragma unroll
            for (int jj = 0; jj < 4; ++jj) {
                int k0 = kc * 32 + q * 8 + 2 * jj;
                float t0 = fmaxf(dw2[k0]     * (ws[256 + k0]     * inv_n), 0.f);
                float t1 = fmaxf(dw2[k0 + 1] * (ws[256 + k0 + 1] * inv_n), 0.f);
                t.u[jj] = pack_trunc(t0, t1);
            }
            axg[kc] = t.v;
        }
#pragma unroll
        for (int nt = 0; nt < 4; ++nt) {
            s16x8 b0, b1;
            const float* src0 = pw2 + (nt * 16 + m) * C + q * 8;
            const float* src1 = src0 + 32;
            float4 p0 = *(const float4*)src0, p1 = *(const float4*)(src0 + 4);
            float4 p2 = *(const float4*)src1, p3 = *(const float4*)(src1 + 4);
            b0[0] = f2bf(p0.x); b0[1] = f2bf(p0.y); b0[2] = f2bf(p0.z); b0[3] = f2bf(p0.w);
            b0[4] = f2bf(p1.x); b0[5] = f2bf(p1.y); b0[6] = f2bf(p1.z); b0[7] = f2bf(p1.w);
            b1[0] = f2bf(p2.x); b1[1] = f2bf(p2.y); b1[2] = f2bf(p2.z); b1[3] = f2bf(p2.w);
            b1[4] = f2bf(p3.x); b1[5] = f2bf(p3.y); b1[6] = f2bf(p3.z); b1[7] = f2bf(p3.w);
            f32x4 acc = __builtin_amdgcn_mfma_f32_16x16x32_bf16(axg[0], b0, zero, 0, 0, 0);
            acc = __builtin_amdgcn_mfma_f32_16x16x32_bf16(axg[1], b1, acc, 0, 0, 0);
            xgv[nt] = acc[0];     // all C-rows identical; take reg 0
        }
    }

    __shared__ float sb[2][16 * LD];
    float* my = sb[wv];

    const int w  = blockIdx.x * 2 + wv;    // 0..14999
    const int s0 = w * SEGW;

    int st1 = starts[s0 + 1];
    int st2 = (s0 + 2 < NSEG) ? starts[s0 + 2] : N_PTS;
    const int start   = starts[s0];
    const int end_all = st2;

    int cur = s0;
    int end_cur = st1;

    float sm[4]  = {0.f, 0.f, 0.f, 0.f};
    float mxv[4] = {-INFINITY, -INFINITY, -INFINITY, -INFINITY};

    auto flushseg = [&](int s) {
#pragma unroll
        for (int nt = 0; nt < 4; ++nt) {
            sm[nt] += __shfl_xor(sm[nt], 16, 64);
            sm[nt] += __shfl_xor(sm[nt], 32, 64);
            mxv[nt] = fmaxf(mxv[nt], __shfl_xor(mxv[nt], 16, 64));
            mxv[nt] = fmaxf(mxv[nt], __shfl_xor(mxv[nt], 32, 64));
        }
        float S = sm[0], M = mxv[0];
        if (q == 1) { S = sm[1]; M = mxv[1]; }
        if (q == 2) { S = sm[2]; M = mxv[2]; }
        if (q == 3) { S = sm[3]; M = mxv[3]; }
        out[(size_t)s * C + lane] = S + M;
#pragma unroll
        for (int nt = 0; nt < 4; ++nt) { sm[nt] = 0.f; mxv[nt] = -INFINITY; }
    };

    float2 P0, P1, P2, P3;
    auto loadrows = [&](int pb) {
        const float* row = inp + (size_t)min(pb + m, N_PTS - 1) * CI;
        if (q == 0) {
            P0 = *(const float2*)(row);     P1 = *(const float2*)(row + 2);
            P2 = *(const float2*)(row + 4); P3 = *(const float2*)(row + 6);
        } else if (q == 1) {
            P0 = *(const float2*)(row + 8);
        }
    };
    P0 = P1 = P2 = P3 = make_float2(0.f, 0.f);
    loadrows(start);

    for (int base = start; base < end_all; base += 16) {
        float2 L0 = P0, L1 = P1, L2 = P2, L3 = P3;
        if (base + 16 < end_all) loadrows(base + 16);

        const int nb = min(16, end_all - base);

        // ---- A-frag of rows (K padded to 32, truncation pack)
        union { s16x8 v; unsigned u[4]; } t;
        t.v = s16x8{0, 0, 0, 0, 0, 0, 0, 0};
        if (q < 2) t.u[0] = pack_trunc(L0.x, L0.y);
        if (q == 0) {
            t.u[1] = pack_trunc(L1.x, L1.y);
            t.u[2] = pack_trunc(L2.x, L2.y);
            t.u[3] = pack_trunc(L3.x, L3.y);
        }

        // ---- x' = rows @ W'^T  (C-layout: ch=16nt+m, pt=4q+r)
        f32x4 xt[4];
#pragma unroll
        for (int nt = 0; nt < 4; ++nt)
            xt[nt] = __builtin_amdgcn_mfma_f32_16x16x32_bf16(t.v, wfr[nt], zero, 0, 0, 0);

        // ---- BN + ReLU + swish; sw -> LDS tile [pt][ch]
        float xn[4][4];
#pragma unroll
        for (int nt = 0; nt < 4; ++nt)
#pragma unroll
            for (int r = 0; r < 4; ++r) {
                float x = fmaxf(xt[nt][r] + bb[nt], 0.f);
                xn[nt][r] = x;
                float sg = x * d1v[nt];
                float sw = sg * frcp(1.f + __expf(-sg));
                my[(4 * q + r) * LD + nt * 16 + m] = sw;
            }
        __threadfence_block();

        // ---- A-frags of sw: lane(m,q) reads sw[pt=m][32kc+8q+j]
        s16x8 av[2];
#pragma unroll
        for (int kc = 0; kc < 2; ++kc) {
            const float* src = &my[m * LD + kc * 32 + q * 8];
            float4 p0 = *(const float4*)src;
            float4 p1 = *(const float4*)(src + 4);
            union { s16x8 v; unsigned u[4]; } tt;
            tt.u[0] = pack_trunc(p0.x, p0.y);
            tt.u[1] = pack_trunc(p0.z, p0.w);
            tt.u[2] = pack_trunc(p1.x, p1.y);
            tt.u[3] = pack_trunc(p1.z, p1.w);
            av[kc] = tt.v;
        }

        // ---- xl = sw @ pw1^T (C-layout, aligned with xn) -> xi in place
        f32x4 xi[4];
#pragma unroll
        for (int nt = 0; nt < 4; ++nt) {
            xi[nt] = __builtin_amdgcn_mfma_f32_16x16x32_bf16(av[0], bfr[nt][0], zero, 0, 0, 0);
            xi[nt] = __builtin_amdgcn_mfma_f32_16x16x32_bf16(av[1], bfr[nt][1], xi[nt], 0, 0, 0);
        }
        __threadfence_block();

#pragma unroll
        for (int nt = 0; nt < 4; ++nt)
#pragma unroll
            for (int r = 0; r < 4; ++r) {
                float v   = xi[nt][r] + xgv[nt];
                float wei = frcp(1.f + __expf(-v));
                float x   = xn[nt][r];
                xi[nt][r] = fmaf(x, wei, x);
            }

        // ---- segmented accumulate (<=1 boundary per batch: min seg len 33)
        const int fin = base + nb;
        if (fin <= end_cur) {
            if (nb == 16) {
#pragma unroll
                for (int nt = 0; nt < 4; ++nt)
#pragma unroll
                    for (int r = 0; r < 4; ++r) {
                        sm[nt] += xi[nt][r];
                        mxv[nt] = fmaxf(mxv[nt], xi[nt][r]);
                    }
            } else {
#pragma unroll
                for (int nt = 0; nt < 4; ++nt)
#pragma unroll
                    for (int r = 0; r < 4; ++r) {
                        bool act = (4 * q + r) < nb;
                        sm[nt] += act ? xi[nt][r] : 0.f;
                        mxv[nt] = fmaxf(mxv[nt], act ? xi[nt][r] : -INFINITY);
                    }
            }
            if (fin == end_cur) { flushseg(cur); ++cur; end_cur = st2; }
        } else {
            const int B = end_cur - base;   // 1..nb-1
#pragma unroll
            for (int nt = 0; nt < 4; ++nt)
#pragma unroll
                for (int r = 0; r < 4; ++r) {
                    bool act = (4 * q + r) < B;
                    sm[nt] += act ? xi[nt][r] : 0.f;
                    mxv[nt] = fmaxf(mxv[nt], act ? xi[nt][r] : -INFINITY);
                }
            flushseg(cur); ++cur;
#pragma unroll
            for (int nt = 0; nt < 4; ++nt)
#pragma unroll
                for (int r = 0; r < 4; ++r) {
                    int pt = 4 * q + r;
                    bool act = (pt >= B) && (pt < nb);
                    sm[nt] += act ? xi[nt][r] : 0.f;
                    mxv[nt] = fmaxf(mxv[nt], act ? xi[nt][r] : -INFINITY);
                }
            end_cur = st2;
        }
    }
}

extern "C" void kernel_launch(void* const* d_in, const int* in_sizes, int n_in,
                              void* d_out, int out_size, void* d_ws, size_t ws_size,
                              hipStream_t stream) {
    const float* inp   = (const float*)d_in[0];
    const int*   unq   = (const int*)d_in[1];
    const float* W     = (const float*)d_in[2];
    const float* gamma = (const float*)d_in[3];
    const float* beta  = (const float*)d_in[4];
    const float* dw1   = (const float*)d_in[5];
    const float* pw1   = (const float*)d_in[6];
    const float* dw2   = (const float*)d_in[7];
    const float* pw2   = (const float*)d_in[8];
    float* out = (float*)d_out;
    float* ws  = (float*)d_ws;
    int* starts = (int*)ws + 1024;

    hipMemsetAsync(ws, 0, 384 * sizeof(float), stream);   // zero accumulators

    k_moments <<<512,  256, 0, stream>>>(inp, unq, ws, starts);
    k_gstats  <<<512,  256, 0, stream>>>(inp, W, gamma, beta, ws);
    k_main    <<<7500, 128, 0, stream>>>(inp, dw1, pw1, dw2, pw2, ws, starts, out);
}

// Round 7
// 285.265 us; speedup vs baseline: 1.1985x; 1.1985x over previous
//
#include <hip/hip_runtime.h>
#include <math.h>

#define N_PTS   1000000
#define CI      10
#define C       64
#define NSEG    30000
#define BN_EPS  1e-3f
#define FROFF   31104      // float index of fragment blob (after starts ints)

// ws layout (floats):
// [0:10)    colsum(inp)              (accumulator, zeroed)
// [10:65)   M = sum row*row^T, upper-tri i<=j row-major (55)  (zeroed)
// [128:192) a = rstd*gamma
// [192:256) b = beta - mu*a
// [256:320) g_sum                    (accumulator, zeroed)
// [384:1024) W' = a*W  (64x10, row-major)
// ints at [1024:31024): segment starts
// [FROFF : FROFF+15*256): per-lane fragment blob, 15 items x 64 lanes x 16B

using f32x4 = __attribute__((ext_vector_type(4))) float;
using s16x8 = __attribute__((ext_vector_type(8))) short;

__device__ inline short f2bf(float x) {           // RNE fp32 -> bf16 (weights)
    unsigned u = __float_as_uint(x);
    unsigned r = (u + 0x7fffu + ((u >> 16) & 1u)) >> 16;
    return (short)r;
}
__device__ inline unsigned pack_trunc(float lo, float hi) {  // 2x bf16 truncate
    return (__float_as_uint(hi) & 0xffff0000u) | (__float_as_uint(lo) >> 16);
}
__device__ inline float frcp(float x) { return __builtin_amdgcn_rcpf(x); }

// Kernel 1: colsum[10] + second-moment M[55] of raw inputs (BN stats from 65
// scalars since linear commutes with the point-sum). Fused: segment starts.
__global__ void __launch_bounds__(256) k_moments(const float* __restrict__ inp,
                                                 const int* __restrict__ idx,
                                                 float* __restrict__ ws,
                                                 int* __restrict__ starts) {
    const int tid = threadIdx.x;
    float v[65];
#pragma unroll
    for (int k = 0; k < 65; ++k) v[k] = 0.f;

    for (int p = blockIdx.x * blockDim.x + tid; p < N_PTS; p += gridDim.x * blockDim.x) {
        const float2* r2 = (const float2*)(inp + (size_t)p * CI);
        float2 a0 = r2[0], a1 = r2[1], a2 = r2[2], a3 = r2[3], a4 = r2[4];
        float r[CI] = {a0.x, a0.y, a1.x, a1.y, a2.x, a2.y, a3.x, a3.y, a4.x, a4.y};
#pragma unroll
        for (int i = 0; i < CI; ++i) v[i] += r[i];
        int kk = 10;
#pragma unroll
        for (int i = 0; i < CI; ++i)
#pragma unroll
            for (int j = i; j < CI; ++j) { v[kk] = fmaf(r[i], r[j], v[kk]); ++kk; }

        int iv = idx[p];
        if (p == 0) starts[0] = 0;
        else if (idx[p - 1] != iv) starts[iv] = p;
    }

#pragma unroll
    for (int k = 0; k < 65; ++k) {
#pragma unroll
        for (int off = 32; off >= 1; off >>= 1)
            v[k] += __shfl_xor(v[k], off, 64);
    }
    __shared__ float red[4 * 65];
    const int wv = tid >> 6, ln = tid & 63;
    if (ln == 0) {
#pragma unroll
        for (int k = 0; k < 65; ++k) red[wv * 65 + k] = v[k];
    }
    __syncthreads();
    if (tid < 65)
        atomicAdd(&ws[tid], red[tid] + red[65 + tid] + red[130 + tid] + red[195 + tid]);
}

// Kernel 2 (fused finalize + gstats): per-block BN finalize from the 65
// moments, then g_sum[c] = sum_p relu(x'_pc + b_c) via MFMA linear.
__global__ void __launch_bounds__(256) k_gstats(const float* __restrict__ inp,
                                                const float* __restrict__ W,
                                                const float* __restrict__ gamma,
                                                const float* __restrict__ beta,
                                                float* __restrict__ ws) {
    const int tid  = threadIdx.x;
    const int wv   = tid >> 6;
    const int lane = tid & 63;
    const int m = lane & 15;
    const int q = lane >> 4;

    __shared__ float wp[C * CI];   // W' = a*W
    __shared__ float bsh[C];

    if (tid < C) {
        const int c = tid;
        float w[CI];
#pragma unroll
        for (int i = 0; i < CI; ++i) w[i] = W[c * CI + i];
        const float inv_n = 1.f / (float)N_PTS;

        float mu = 0.f;
#pragma unroll
        for (int i = 0; i < CI; ++i) mu = fmaf(w[i], ws[i], mu);
        mu *= inv_n;

        float ex2 = 0.f;
        int kk = 10;
#pragma unroll
        for (int i = 0; i < CI; ++i)
#pragma unroll
            for (int j = i; j < CI; ++j) {
                float mm = ws[kk];
                float t = w[i] * w[j] * mm;
                ex2 += (i == j) ? t : 2.f * t;
                ++kk;
            }
        ex2 *= inv_n;

        float var = ex2 - mu * mu;
        float rstd = rsqrtf(var + BN_EPS);
        float a = rstd * gamma[c];
        float b = beta[c] - mu * a;
        bsh[c] = b;
        ws[128 + c] = a;
        ws[192 + c] = b;
#pragma unroll
        for (int i = 0; i < CI; ++i) {
            float wi = a * w[i];
            wp[c * CI + i] = wi;
            ws[384 + c * CI + i] = wi;
        }
    }
    __syncthreads();

    s16x8 wfr[4];
#pragma unroll
    for (int nt = 0; nt < 4; ++nt) {
        s16x8 t;
#pragma unroll
        for (int j = 0; j < 8; ++j) {
            int k = 8 * q + j;
            t[j] = (k < CI) ? f2bf(wp[(nt * 16 + m) * CI + k]) : (short)0;
        }
        wfr[nt] = t;
    }
    float bb[4];
#pragma unroll
    for (int nt = 0; nt < 4; ++nt) bb[nt] = bsh[nt * 16 + m];

    const int wid = blockIdx.x * 4 + wv;
    const int nw  = gridDim.x * 4;
    const int NB  = N_PTS / 16;          // 62500

    float2 P0, P1, P2, P3;
    auto loadrows = [&](int pb) {
        const float* row = inp + (size_t)(pb + m) * CI;
        if (q == 0) {
            P0 = *(const float2*)(row);     P1 = *(const float2*)(row + 2);
            P2 = *(const float2*)(row + 4); P3 = *(const float2*)(row + 6);
        } else if (q == 1) {
            P0 = *(const float2*)(row + 8);
        }
    };
    P0 = P1 = P2 = P3 = make_float2(0.f, 0.f);

    float sm[4] = {0.f, 0.f, 0.f, 0.f};
    const f32x4 zero = {0.f, 0.f, 0.f, 0.f};

    if (wid < NB) loadrows(wid * 16);
    for (int b = wid; b < NB; b += nw) {
        float2 L0 = P0, L1 = P1, L2 = P2, L3 = P3;
        if (b + nw < NB) loadrows((b + nw) * 16);

        union { s16x8 v; unsigned u[4]; } t;
        t.v = s16x8{0, 0, 0, 0, 0, 0, 0, 0};
        if (q < 2) t.u[0] = pack_trunc(L0.x, L0.y);
        if (q == 0) {
            t.u[1] = pack_trunc(L1.x, L1.y);
            t.u[2] = pack_trunc(L2.x, L2.y);
            t.u[3] = pack_trunc(L3.x, L3.y);
        }

        f32x4 xt[4];
#pragma unroll
        for (int nt = 0; nt < 4; ++nt) {
            xt[nt] = __builtin_amdgcn_mfma_f32_16x16x32_bf16(t.v, wfr[nt], zero, 0, 0, 0);
#pragma unroll
            for (int r = 0; r < 4; ++r)
                sm[nt] += fmaxf(xt[nt][r] + bb[nt], 0.f);
        }
    }

#pragma unroll
    for (int nt = 0; nt < 4; ++nt) {
        sm[nt] += __shfl_xor(sm[nt], 16, 64);
        sm[nt] += __shfl_xor(sm[nt], 32, 64);
    }
    float S = sm[0];
    if (q == 1) S = sm[1];
    if (q == 2) S = sm[2];
    if (q == 3) S = sm[3];

    __shared__ float red[4 * 64];
    red[wv * 64 + lane] = S;              // lane == channel
    __syncthreads();
    if (tid < 64)
        atomicAdd(&ws[256 + tid], red[tid] + red[64 + tid] + red[128 + tid] + red[192 + tid]);
}

// Kernel 3: k_prep — fp32 xg + all per-lane fragments for k_main, stored as
// [item][lane] 16B records (coalesced dwordx4 loads in k_main).
// items 0..3: wfr[nt]; 4..11: bfr[nt][kc] (idx 4+2nt+kc); 12: bb; 13: d1v; 14: xgv
__global__ void k_prep(const float* __restrict__ dw1,
                       const float* __restrict__ pw1,
                       const float* __restrict__ dw2,
                       const float* __restrict__ pw2,
                       float* __restrict__ ws) {
    const int lane = threadIdx.x;     // 0..63
    const int m = lane & 15, q = lane >> 4;
    __shared__ float t[C], xgs[C];
    const float inv_n = 1.f / (float)N_PTS;
    t[lane] = fmaxf(dw2[lane] * (ws[256 + lane] * inv_n), 0.f);
    __syncthreads();
    float acc = 0.f;
#pragma unroll
    for (int k = 0; k < C; ++k) acc = fmaf(pw2[lane * C + k], t[k], acc);
    xgs[lane] = acc;
    __syncthreads();

    float4* FR = (float4*)(ws + FROFF);
    union { float4 f; s16x8 v; } u;

#pragma unroll
    for (int nt = 0; nt < 4; ++nt) {
        s16x8 tt;
#pragma unroll
        for (int j = 0; j < 8; ++j) {
            int k = 8 * q + j;
            tt[j] = (k < CI) ? f2bf(ws[384 + (nt * 16 + m) * CI + k]) : (short)0;
        }
        u.v = tt; FR[nt * 64 + lane] = u.f;
    }
#pragma unroll
    for (int nt = 0; nt < 4; ++nt)
#pragma unroll
        for (int kc = 0; kc < 2; ++kc) {
            const float* src = pw1 + (nt * 16 + m) * C + kc * 32 + q * 8;
            float4 p0 = *(const float4*)src, p1 = *(const float4*)(src + 4);
            s16x8 tt;
            tt[0] = f2bf(p0.x); tt[1] = f2bf(p0.y); tt[2] = f2bf(p0.z); tt[3] = f2bf(p0.w);
            tt[4] = f2bf(p1.x); tt[5] = f2bf(p1.y); tt[6] = f2bf(p1.z); tt[7] = f2bf(p1.w);
            u.v = tt; FR[(4 + nt * 2 + kc) * 64 + lane] = u.f;
        }
    float4 f;
    f.x = ws[192 + m]; f.y = ws[192 + 16 + m]; f.z = ws[192 + 32 + m]; f.w = ws[192 + 48 + m];
    FR[12 * 64 + lane] = f;
    f.x = dw1[m]; f.y = dw1[16 + m]; f.z = dw1[32 + m]; f.w = dw1[48 + m];
    FR[13 * 64 + lane] = f;
    f.x = xgs[m]; f.y = xgs[16 + m]; f.z = xgs[32 + m]; f.w = xgs[48 + m];
    FR[14 * 64 + lane] = f;
}

// Kernel 4: k_main — one wave per 2 contiguous segments, streaming 16-pt
// batches across the boundary with segmented sum/max. Prologue = 15 coalesced
// dwordx4 loads of precomputed fragments (no conversion ALU).
#define LD 68
#define SEGW 2
__global__ void __launch_bounds__(128) k_main(const float* __restrict__ inp,
                                              const float* __restrict__ ws,
                                              const int* __restrict__ starts,
                                              float* __restrict__ out) {
    const int tid  = threadIdx.x;
    const int wv   = tid >> 6;
    const int lane = tid & 63;
    const int m = lane & 15;
    const int q = lane >> 4;
    const f32x4 zero = {0.f, 0.f, 0.f, 0.f};

    const float4* FR = (const float4*)(ws + FROFF);
    union { float4 f; s16x8 v; } u;
    s16x8 wfr[4];
#pragma unroll
    for (int nt = 0; nt < 4; ++nt) { u.f = FR[nt * 64 + lane]; wfr[nt] = u.v; }
    s16x8 bfr[4][2];
#pragma unroll
    for (int nt = 0; nt < 4; ++nt)
#pragma unroll
        for (int kc = 0; kc < 2; ++kc) { u.f = FR[(4 + nt * 2 + kc) * 64 + lane]; bfr[nt][kc] = u.v; }
    const float4 bb4  = FR[12 * 64 + lane];
    const float4 d14  = FR[13 * 64 + lane];
    const float4 xg4  = FR[14 * 64 + lane];
    const float bb[4]  = {bb4.x, bb4.y, bb4.z, bb4.w};
    const float d1v[4] = {d14.x, d14.y, d14.z, d14.w};
    const float xgv[4] = {xg4.x, xg4.y, xg4.z, xg4.w};

    __shared__ float sb[2][16 * LD];
    float* my = sb[wv];

    const int w  = blockIdx.x * 2 + wv;    // 0..14999
    const int s0 = w * SEGW;

    int st1 = starts[s0 + 1];
    int st2 = (s0 + 2 < NSEG) ? starts[s0 + 2] : N_PTS;
    const int start   = starts[s0];
    const int end_all = st2;

    int cur = s0;
    int end_cur = st1;

    float sm[4]  = {0.f, 0.f, 0.f, 0.f};
    float mxv[4] = {-INFINITY, -INFINITY, -INFINITY, -INFINITY};

    auto flushseg = [&](int s) {
#pragma unroll
        for (int nt = 0; nt < 4; ++nt) {
            sm[nt] += __shfl_xor(sm[nt], 16, 64);
            sm[nt] += __shfl_xor(sm[nt], 32, 64);
            mxv[nt] = fmaxf(mxv[nt], __shfl_xor(mxv[nt], 16, 64));
            mxv[nt] = fmaxf(mxv[nt], __shfl_xor(mxv[nt], 32, 64));
        }
        float S = sm[0], M = mxv[0];
        if (q == 1) { S = sm[1]; M = mxv[1]; }
        if (q == 2) { S = sm[2]; M = mxv[2]; }
        if (q == 3) { S = sm[3]; M = mxv[3]; }
        out[(size_t)s * C + lane] = S + M;
#pragma unroll
        for (int nt = 0; nt < 4; ++nt) { sm[nt] = 0.f; mxv[nt] = -INFINITY; }
    };

    float2 P0, P1, P2, P3;
    auto loadrows = [&](int pb) {
        const float* row = inp + (size_t)min(pb + m, N_PTS - 1) * CI;
        if (q == 0) {
            P0 = *(const float2*)(row);     P1 = *(const float2*)(row + 2);
            P2 = *(const float2*)(row + 4); P3 = *(const float2*)(row + 6);
        } else if (q == 1) {
            P0 = *(const float2*)(row + 8);
        }
    };
    P0 = P1 = P2 = P3 = make_float2(0.f, 0.f);
    loadrows(start);

    for (int base = start; base < end_all; base += 16) {
        float2 L0 = P0, L1 = P1, L2 = P2, L3 = P3;
        if (base + 16 < end_all) loadrows(base + 16);

        const int nb = min(16, end_all - base);

        // ---- A-frag of rows (K padded to 32, truncation pack)
        union { s16x8 v; unsigned u[4]; } t;
        t.v = s16x8{0, 0, 0, 0, 0, 0, 0, 0};
        if (q < 2) t.u[0] = pack_trunc(L0.x, L0.y);
        if (q == 0) {
            t.u[1] = pack_trunc(L1.x, L1.y);
            t.u[2] = pack_trunc(L2.x, L2.y);
            t.u[3] = pack_trunc(L3.x, L3.y);
        }

        // ---- x' = rows @ W'^T  (C-layout: ch=16nt+m, pt=4q+r)
        f32x4 xt[4];
#pragma unroll
        for (int nt = 0; nt < 4; ++nt)
            xt[nt] = __builtin_amdgcn_mfma_f32_16x16x32_bf16(t.v, wfr[nt], zero, 0, 0, 0);

        // ---- BN + ReLU + swish; sw -> LDS tile [pt][ch]
        float xn[4][4];
#pragma unroll
        for (int nt = 0; nt < 4; ++nt)
#pragma unroll
            for (int r = 0; r < 4; ++r) {
                float x = fmaxf(xt[nt][r] + bb[nt], 0.f);
                xn[nt][r] = x;
                float sg = x * d1v[nt];
                float sw = sg * frcp(1.f + __expf(-sg));
                my[(4 * q + r) * LD + nt * 16 + m] = sw;
            }
        __threadfence_block();

        // ---- A-frags of sw: lane(m,q) reads sw[pt=m][32kc+8q+j]
        s16x8 av[2];
#pragma unroll
        for (int kc = 0; kc < 2; ++kc) {
            const float* src = &my[m * LD + kc * 32 + q * 8];
            float4 p0 = *(const float4*)src;
            float4 p1 = *(const float4*)(src + 4);
            union { s16x8 v; unsigned u[4]; } tt;
            tt.u[0] = pack_trunc(p0.x, p0.y);
            tt.u[1] = pack_trunc(p0.z, p0.w);
            tt.u[2] = pack_trunc(p1.x, p1.y);
            tt.u[3] = pack_trunc(p1.z, p1.w);
            av[kc] = tt.v;
        }

        // ---- xl = sw @ pw1^T (C-layout, aligned with xn)
        f32x4 xi[4];
#pragma unroll
        for (int nt = 0; nt < 4; ++nt) {
            xi[nt] = __builtin_amdgcn_mfma_f32_16x16x32_bf16(av[0], bfr[nt][0], zero, 0, 0, 0);
            xi[nt] = __builtin_amdgcn_mfma_f32_16x16x32_bf16(av[1], bfr[nt][1], xi[nt], 0, 0, 0);
        }
        __threadfence_block();

#pragma unroll
        for (int nt = 0; nt < 4; ++nt)
#pragma unroll
            for (int r = 0; r < 4; ++r) {
                float v   = xi[nt][r] + xgv[nt];
                float wei = frcp(1.f + __expf(-v));
                float x   = xn[nt][r];
                xi[nt][r] = fmaf(x, wei, x);
            }

        // ---- segmented accumulate (<=1 boundary per batch: min seg len 33)
        const int fin = base + nb;
        if (fin <= end_cur) {
            if (nb == 16) {
#pragma unroll
                for (int nt = 0; nt < 4; ++nt)
#pragma unroll
                    for (int r = 0; r < 4; ++r) {
                        sm[nt] += xi[nt][r];
                        mxv[nt] = fmaxf(mxv[nt], xi[nt][r]);
                    }
            } else {
#pragma unroll
                for (int nt = 0; nt < 4; ++nt)
#pragma unroll
                    for (int r = 0; r < 4; ++r) {
                        bool act = (4 * q + r) < nb;
                        sm[nt] += act ? xi[nt][r] : 0.f;
                        mxv[nt] = fmaxf(mxv[nt], act ? xi[nt][r] : -INFINITY);
                    }
            }
            if (fin == end_cur) { flushseg(cur); ++cur; end_cur = st2; }
        } else {
            const int B = end_cur - base;   // 1..nb-1
#pragma unroll
            for (int nt = 0; nt < 4; ++nt)
#pragma unroll
                for (int r = 0; r < 4; ++r) {
                    bool act = (4 * q + r) < B;
                    sm[nt] += act ? xi[nt][r] : 0.f;
                    mxv[nt] = fmaxf(mxv[nt], act ? xi[nt][r] : -INFINITY);
                }
            flushseg(cur); ++cur;
#pragma unroll
            for (int nt = 0; nt < 4; ++nt)
#pragma unroll
                for (int r = 0; r < 4; ++r) {
                    int pt = 4 * q + r;
                    bool act = (pt >= B) && (pt < nb);
                    sm[nt] += act ? xi[nt][r] : 0.f;
                    mxv[nt] = fmaxf(mxv[nt], act ? xi[nt][r] : -INFINITY);
                }
            end_cur = st2;
        }
    }
}

extern "C" void kernel_launch(void* const* d_in, const int* in_sizes, int n_in,
                              void* d_out, int out_size, void* d_ws, size_t ws_size,
                              hipStream_t stream) {
    const float* inp   = (const float*)d_in[0];
    const int*   unq   = (const int*)d_in[1];
    const float* W     = (const float*)d_in[2];
    const float* gamma = (const float*)d_in[3];
    const float* beta  = (const float*)d_in[4];
    const float* dw1   = (const float*)d_in[5];
    const float* pw1   = (const float*)d_in[6];
    const float* dw2   = (const float*)d_in[7];
    const float* pw2   = (const float*)d_in[8];
    float* out = (float*)d_out;
    float* ws  = (float*)d_ws;
    int* starts = (int*)ws + 1024;

    hipMemsetAsync(ws, 0, 384 * sizeof(float), stream);   // zero accumulators

    k_moments <<<1024, 256, 0, stream>>>(inp, unq, ws, starts);
    k_gstats  <<<1024, 256, 0, stream>>>(inp, W, gamma, beta, ws);
    k_prep    <<<1,    64,  0, stream>>>(dw1, pw1, dw2, pw2, ws);
    k_main    <<<7500, 128, 0, stream>>>(inp, ws, starts, out);
}

// Round 8
// 268.236 us; speedup vs baseline: 1.2745x; 1.0635x over previous
//
#include <hip/hip_runtime.h>
#include <math.h>

#define N_PTS   1000000
#define CI      10
#define C       64
#define NSEG    30000
#define BN_EPS  1e-3f
#define FROFF   31104      // float index of fragment blob (after starts ints)

// ws layout (floats):
// [0:10)    colsum(inp)              (accumulator, zeroed)
// [10:65)   M = sum row*row^T, upper-tri i<=j row-major (55)  (zeroed)
// [256:320) g_sum                    (accumulator, zeroed)
// ints at [1024:31024): segment starts
// [FROFF : FROFF+15*256): per-lane fragment blob, 15 items x 64 lanes x 16B

using f32x4 = __attribute__((ext_vector_type(4))) float;
using s16x8 = __attribute__((ext_vector_type(8))) short;

__device__ inline short f2bf(float x) {           // RNE fp32 -> bf16 (weights)
    unsigned u = __float_as_uint(x);
    unsigned r = (u + 0x7fffu + ((u >> 16) & 1u)) >> 16;
    return (short)r;
}
__device__ inline unsigned pack_trunc(float lo, float hi) {  // 2x bf16 truncate
    return (__float_as_uint(hi) & 0xffff0000u) | (__float_as_uint(lo) >> 16);
}
__device__ inline float frcp(float x) { return __builtin_amdgcn_rcpf(x); }
// LDS-only drain: write->read visibility within a wave, does NOT drain vmcnt
// (unlike __threadfence_block, which emits s_waitcnt vmcnt(0) lgkmcnt(0) and
// was nullifying the global-load prefetch every batch).
__device__ inline void lds_fence() {
    asm volatile("s_waitcnt lgkmcnt(0)" ::: "memory");
}

// Kernel 1: colsum[10] + second-moment M[55] of raw inputs (BN stats from 65
// scalars since linear commutes with the point-sum). Fused: segment starts.
__global__ void __launch_bounds__(256) k_moments(const float* __restrict__ inp,
                                                 const int* __restrict__ idx,
                                                 float* __restrict__ ws,
                                                 int* __restrict__ starts) {
    const int tid = threadIdx.x;
    float v[65];
#pragma unroll
    for (int k = 0; k < 65; ++k) v[k] = 0.f;

    for (int p = blockIdx.x * blockDim.x + tid; p < N_PTS; p += gridDim.x * blockDim.x) {
        const float2* r2 = (const float2*)(inp + (size_t)p * CI);
        float2 a0 = r2[0], a1 = r2[1], a2 = r2[2], a3 = r2[3], a4 = r2[4];
        float r[CI] = {a0.x, a0.y, a1.x, a1.y, a2.x, a2.y, a3.x, a3.y, a4.x, a4.y};
#pragma unroll
        for (int i = 0; i < CI; ++i) v[i] += r[i];
        int kk = 10;
#pragma unroll
        for (int i = 0; i < CI; ++i)
#pragma unroll
            for (int j = i; j < CI; ++j) { v[kk] = fmaf(r[i], r[j], v[kk]); ++kk; }

        int iv = idx[p];
        if (p == 0) starts[0] = 0;
        else if (idx[p - 1] != iv) starts[iv] = p;
    }

#pragma unroll
    for (int k = 0; k < 65; ++k) {
#pragma unroll
        for (int off = 32; off >= 1; off >>= 1)
            v[k] += __shfl_xor(v[k], off, 64);
    }
    __shared__ float red[4 * 65];
    const int wv = tid >> 6, ln = tid & 63;
    if (ln == 0) {
#pragma unroll
        for (int k = 0; k < 65; ++k) red[wv * 65 + k] = v[k];
    }
    __syncthreads();
    if (tid < 65)
        atomicAdd(&ws[tid], red[tid] + red[65 + tid] + red[130 + tid] + red[195 + tid]);
}

// Kernel 2 (fused finalize + gstats): per-block BN finalize from the 65
// moments (LDS ONLY — no global stores, which caused a cross-XCD line storm),
// then g_sum[c] = sum_p relu(x'_pc + b_c) via MFMA linear.
__global__ void __launch_bounds__(256) k_gstats(const float* __restrict__ inp,
                                                const float* __restrict__ W,
                                                const float* __restrict__ gamma,
                                                const float* __restrict__ beta,
                                                float* __restrict__ ws) {
    const int tid  = threadIdx.x;
    const int wv   = tid >> 6;
    const int lane = tid & 63;
    const int m = lane & 15;
    const int q = lane >> 4;

    __shared__ float wp[C * CI];   // W' = a*W
    __shared__ float bsh[C];

    if (tid < C) {
        const int c = tid;
        float w[CI];
#pragma unroll
        for (int i = 0; i < CI; ++i) w[i] = W[c * CI + i];
        const float inv_n = 1.f / (float)N_PTS;

        float mu = 0.f;
#pragma unroll
        for (int i = 0; i < CI; ++i) mu = fmaf(w[i], ws[i], mu);
        mu *= inv_n;

        float ex2 = 0.f;
        int kk = 10;
#pragma unroll
        for (int i = 0; i < CI; ++i)
#pragma unroll
            for (int j = i; j < CI; ++j) {
                float mm = ws[kk];
                float t = w[i] * w[j] * mm;
                ex2 += (i == j) ? t : 2.f * t;
                ++kk;
            }
        ex2 *= inv_n;

        float var = ex2 - mu * mu;
        float rstd = rsqrtf(var + BN_EPS);
        float a = rstd * gamma[c];
        float b = beta[c] - mu * a;
        bsh[c] = b;
#pragma unroll
        for (int i = 0; i < CI; ++i) wp[c * CI + i] = a * w[i];
    }
    __syncthreads();

    s16x8 wfr[4];
#pragma unroll
    for (int nt = 0; nt < 4; ++nt) {
        s16x8 t;
#pragma unroll
        for (int j = 0; j < 8; ++j) {
            int k = 8 * q + j;
            t[j] = (k < CI) ? f2bf(wp[(nt * 16 + m) * CI + k]) : (short)0;
        }
        wfr[nt] = t;
    }
    float bb[4];
#pragma unroll
    for (int nt = 0; nt < 4; ++nt) bb[nt] = bsh[nt * 16 + m];

    const int wid = blockIdx.x * 4 + wv;
    const int nw  = gridDim.x * 4;
    const int NB  = N_PTS / 16;          // 62500

    float2 P0, P1, P2, P3;
    auto loadrows = [&](int pb) {
        const float* row = inp + (size_t)(pb + m) * CI;
        if (q == 0) {
            P0 = *(const float2*)(row);     P1 = *(const float2*)(row + 2);
            P2 = *(const float2*)(row + 4); P3 = *(const float2*)(row + 6);
        } else if (q == 1) {
            P0 = *(const float2*)(row + 8);
        }
    };
    P0 = P1 = P2 = P3 = make_float2(0.f, 0.f);

    float sm[4] = {0.f, 0.f, 0.f, 0.f};
    const f32x4 zero = {0.f, 0.f, 0.f, 0.f};

    if (wid < NB) loadrows(wid * 16);
    for (int b = wid; b < NB; b += nw) {
        float2 L0 = P0, L1 = P1, L2 = P2, L3 = P3;
        if (b + nw < NB) loadrows((b + nw) * 16);

        union { s16x8 v; unsigned u[4]; } t;
        t.v = s16x8{0, 0, 0, 0, 0, 0, 0, 0};
        if (q < 2) t.u[0] = pack_trunc(L0.x, L0.y);
        if (q == 0) {
            t.u[1] = pack_trunc(L1.x, L1.y);
            t.u[2] = pack_trunc(L2.x, L2.y);
            t.u[3] = pack_trunc(L3.x, L3.y);
        }

        f32x4 xt[4];
#pragma unroll
        for (int nt = 0; nt < 4; ++nt) {
            xt[nt] = __builtin_amdgcn_mfma_f32_16x16x32_bf16(t.v, wfr[nt], zero, 0, 0, 0);
#pragma unroll
            for (int r = 0; r < 4; ++r)
                sm[nt] += fmaxf(xt[nt][r] + bb[nt], 0.f);
        }
    }

#pragma unroll
    for (int nt = 0; nt < 4; ++nt) {
        sm[nt] += __shfl_xor(sm[nt], 16, 64);
        sm[nt] += __shfl_xor(sm[nt], 32, 64);
    }
    float S = sm[0];
    if (q == 1) S = sm[1];
    if (q == 2) S = sm[2];
    if (q == 3) S = sm[3];

    __shared__ float red[4 * 64];
    red[wv * 64 + lane] = S;              // lane == channel
    __syncthreads();
    if (tid < 64)
        atomicAdd(&ws[256 + tid], red[tid] + red[64 + tid] + red[128 + tid] + red[192 + tid]);
}

// Kernel 3: k_prep — BN finalize (lane = channel), fp32 xg, and all per-lane
// fragments for k_main, stored as [item][lane] 16B records.
// items 0..3: wfr[nt]; 4..11: bfr[nt][kc] (idx 4+2nt+kc); 12: bb; 13: d1v; 14: xgv
__global__ void k_prep(const float* __restrict__ W,
                       const float* __restrict__ gamma,
                       const float* __restrict__ beta,
                       const float* __restrict__ dw1,
                       const float* __restrict__ pw1,
                       const float* __restrict__ dw2,
                       const float* __restrict__ pw2,
                       float* __restrict__ ws) {
    const int lane = threadIdx.x;     // 0..63 ; lane == channel c
    const int m = lane & 15, q = lane >> 4;
    const float inv_n = 1.f / (float)N_PTS;

    __shared__ float WP[C * CI];   // W' = a*W
    __shared__ float BSH[C], T[C], XG[C];

    // ---- BN finalize for channel `lane`
    {
        float w[CI];
#pragma unroll
        for (int i = 0; i < CI; ++i) w[i] = W[lane * CI + i];
        float mu = 0.f;
#pragma unroll
        for (int i = 0; i < CI; ++i) mu = fmaf(w[i], ws[i], mu);
        mu *= inv_n;
        float ex2 = 0.f;
        int kk = 10;
#pragma unroll
        for (int i = 0; i < CI; ++i)
#pragma unroll
            for (int j = i; j < CI; ++j) {
                float mm = ws[kk];
                float t = w[i] * w[j] * mm;
                ex2 += (i == j) ? t : 2.f * t;
                ++kk;
            }
        ex2 *= inv_n;
        float var = ex2 - mu * mu;
        float rstd = rsqrtf(var + BN_EPS);
        float a = rstd * gamma[lane];
        BSH[lane] = beta[lane] - mu * a;
#pragma unroll
        for (int i = 0; i < CI; ++i) WP[lane * CI + i] = a * w[i];
        T[lane] = fmaxf(dw2[lane] * (ws[256 + lane] * inv_n), 0.f);
    }
    __syncthreads();

    // ---- xg = pw2 @ relu(dw2*g)  (exact fp32)
    {
        float acc = 0.f;
#pragma unroll
        for (int k = 0; k < C; ++k) acc = fmaf(pw2[lane * C + k], T[k], acc);
        XG[lane] = acc;
    }
    __syncthreads();

    float4* FR = (float4*)(ws + FROFF);
    union { float4 f; s16x8 v; } u;

#pragma unroll
    for (int nt = 0; nt < 4; ++nt) {
        s16x8 tt;
#pragma unroll
        for (int j = 0; j < 8; ++j) {
            int k = 8 * q + j;
            tt[j] = (k < CI) ? f2bf(WP[(nt * 16 + m) * CI + k]) : (short)0;
        }
        u.v = tt; FR[nt * 64 + lane] = u.f;
    }
#pragma unroll
    for (int nt = 0; nt < 4; ++nt)
#pragma unroll
        for (int kc = 0; kc < 2; ++kc) {
            const float* src = pw1 + (nt * 16 + m) * C + kc * 32 + q * 8;
            float4 p0 = *(const float4*)src, p1 = *(const float4*)(src + 4);
            s16x8 tt;
            tt[0] = f2bf(p0.x); tt[1] = f2bf(p0.y); tt[2] = f2bf(p0.z); tt[3] = f2bf(p0.w);
            tt[4] = f2bf(p1.x); tt[5] = f2bf(p1.y); tt[6] = f2bf(p1.z); tt[7] = f2bf(p1.w);
            u.v = tt; FR[(4 + nt * 2 + kc) * 64 + lane] = u.f;
        }
    float4 f;
    f.x = BSH[m]; f.y = BSH[16 + m]; f.z = BSH[32 + m]; f.w = BSH[48 + m];
    FR[12 * 64 + lane] = f;
    f.x = dw1[m]; f.y = dw1[16 + m]; f.z = dw1[32 + m]; f.w = dw1[48 + m];
    FR[13 * 64 + lane] = f;
    f.x = XG[m]; f.y = XG[16 + m]; f.z = XG[32 + m]; f.w = XG[48 + m];
    FR[14 * 64 + lane] = f;
}

// Kernel 4: k_main — one wave per 2 contiguous segments, streaming 16-pt
// batches across the boundary with segmented sum/max. 2-deep row prefetch;
// LDS-only fences (lgkmcnt) so prefetch loads stay in flight across batches.
#define LD 68
#define SEGW 2
struct Rows { float2 r0, r1, r2, r3; };
__global__ void __launch_bounds__(128) k_main(const float* __restrict__ inp,
                                              const float* __restrict__ ws,
                                              const int* __restrict__ starts,
                                              float* __restrict__ out) {
    const int tid  = threadIdx.x;
    const int wv   = tid >> 6;
    const int lane = tid & 63;
    const int m = lane & 15;
    const int q = lane >> 4;
    const f32x4 zero = {0.f, 0.f, 0.f, 0.f};

    const float4* FR = (const float4*)(ws + FROFF);
    union { float4 f; s16x8 v; } u;
    s16x8 wfr[4];
#pragma unroll
    for (int nt = 0; nt < 4; ++nt) { u.f = FR[nt * 64 + lane]; wfr[nt] = u.v; }
    s16x8 bfr[4][2];
#pragma unroll
    for (int nt = 0; nt < 4; ++nt)
#pragma unroll
        for (int kc = 0; kc < 2; ++kc) { u.f = FR[(4 + nt * 2 + kc) * 64 + lane]; bfr[nt][kc] = u.v; }
    const float4 bb4  = FR[12 * 64 + lane];
    const float4 d14  = FR[13 * 64 + lane];
    const float4 xg4  = FR[14 * 64 + lane];
    const float bb[4]  = {bb4.x, bb4.y, bb4.z, bb4.w};
    const float d1v[4] = {d14.x, d14.y, d14.z, d14.w};
    const float xgv[4] = {xg4.x, xg4.y, xg4.z, xg4.w};

    __shared__ float sb[2][16 * LD];
    float* my = sb[wv];

    const int w  = blockIdx.x * 2 + wv;    // 0..14999
    const int s0 = w * SEGW;

    int st1 = starts[s0 + 1];
    int st2 = (s0 + 2 < NSEG) ? starts[s0 + 2] : N_PTS;
    const int start   = starts[s0];
    const int end_all = st2;

    int cur = s0;
    int end_cur = st1;

    float sm[4]  = {0.f, 0.f, 0.f, 0.f};
    float mxv[4] = {-INFINITY, -INFINITY, -INFINITY, -INFINITY};

    auto flushseg = [&](int s) {
#pragma unroll
        for (int nt = 0; nt < 4; ++nt) {
            sm[nt] += __shfl_xor(sm[nt], 16, 64);
            sm[nt] += __shfl_xor(sm[nt], 32, 64);
            mxv[nt] = fmaxf(mxv[nt], __shfl_xor(mxv[nt], 16, 64));
            mxv[nt] = fmaxf(mxv[nt], __shfl_xor(mxv[nt], 32, 64));
        }
        float S = sm[0], M = mxv[0];
        if (q == 1) { S = sm[1]; M = mxv[1]; }
        if (q == 2) { S = sm[2]; M = mxv[2]; }
        if (q == 3) { S = sm[3]; M = mxv[3]; }
        out[(size_t)s * C + lane] = S + M;
#pragma unroll
        for (int nt = 0; nt < 4; ++nt) { sm[nt] = 0.f; mxv[nt] = -INFINITY; }
    };

    auto loadrows = [&](int pb) -> Rows {
        Rows R;
        R.r0 = R.r1 = R.r2 = R.r3 = make_float2(0.f, 0.f);
        const float* row = inp + (size_t)min(pb + m, N_PTS - 1) * CI;
        if (q == 0) {
            R.r0 = *(const float2*)(row);     R.r1 = *(const float2*)(row + 2);
            R.r2 = *(const float2*)(row + 4); R.r3 = *(const float2*)(row + 6);
        } else if (q == 1) {
            R.r0 = *(const float2*)(row + 8);
        }
        return R;
    };

    Rows A = loadrows(start);
    Rows B = (start + 16 < end_all) ? loadrows(start + 16) : A;

    for (int base = start; base < end_all; base += 16) {
        Rows L = A;
        A = B;
        if (base + 32 < end_all) B = loadrows(base + 32);

        const int nb = min(16, end_all - base);

        // ---- A-frag of rows (K padded to 32, truncation pack)
        union { s16x8 v; unsigned u[4]; } t;
        t.v = s16x8{0, 0, 0, 0, 0, 0, 0, 0};
        if (q < 2) t.u[0] = pack_trunc(L.r0.x, L.r0.y);
        if (q == 0) {
            t.u[1] = pack_trunc(L.r1.x, L.r1.y);
            t.u[2] = pack_trunc(L.r2.x, L.r2.y);
            t.u[3] = pack_trunc(L.r3.x, L.r3.y);
        }

        // ---- x' = rows @ W'^T  (C-layout: ch=16nt+m, pt=4q+r)
        f32x4 xt[4];
#pragma unroll
        for (int nt = 0; nt < 4; ++nt)
            xt[nt] = __builtin_amdgcn_mfma_f32_16x16x32_bf16(t.v, wfr[nt], zero, 0, 0, 0);

        // ---- BN + ReLU + swish; sw -> LDS tile [pt][ch]
        float xn[4][4];
#pragma unroll
        for (int nt = 0; nt < 4; ++nt)
#pragma unroll
            for (int r = 0; r < 4; ++r) {
                float x = fmaxf(xt[nt][r] + bb[nt], 0.f);
                xn[nt][r] = x;
                float sg = x * d1v[nt];
                float sw = sg * frcp(1.f + __expf(-sg));
                my[(4 * q + r) * LD + nt * 16 + m] = sw;
            }
        lds_fence();

        // ---- A-frags of sw: lane(m,q) reads sw[pt=m][32kc+8q+j]
        s16x8 av[2];
#pragma unroll
        for (int kc = 0; kc < 2; ++kc) {
            const float* src = &my[m * LD + kc * 32 + q * 8];
            float4 p0 = *(const float4*)src;
            float4 p1 = *(const float4*)(src + 4);
            union { s16x8 v; unsigned u[4]; } tt;
            tt.u[0] = pack_trunc(p0.x, p0.y);
            tt.u[1] = pack_trunc(p0.z, p0.w);
            tt.u[2] = pack_trunc(p1.x, p1.y);
            tt.u[3] = pack_trunc(p1.z, p1.w);
            av[kc] = tt.v;
        }

        // ---- xl = sw @ pw1^T (C-layout, aligned with xn)
        f32x4 xi[4];
#pragma unroll
        for (int nt = 0; nt < 4; ++nt) {
            xi[nt] = __builtin_amdgcn_mfma_f32_16x16x32_bf16(av[0], bfr[nt][0], zero, 0, 0, 0);
            xi[nt] = __builtin_amdgcn_mfma_f32_16x16x32_bf16(av[1], bfr[nt][1], xi[nt], 0, 0, 0);
        }
        lds_fence();   // reads drained before next batch overwrites the tile

#pragma unroll
        for (int nt = 0; nt < 4; ++nt)
#pragma unroll
            for (int r = 0; r < 4; ++r) {
                float v   = xi[nt][r] + xgv[nt];
                float wei = frcp(1.f + __expf(-v));
                float x   = xn[nt][r];
                xi[nt][r] = fmaf(x, wei, x);
            }

        // ---- segmented accumulate (<=1 boundary per batch: min seg len 33)
        const int fin = base + nb;
        if (fin <= end_cur) {
            if (nb == 16) {
#pragma unroll
                for (int nt = 0; nt < 4; ++nt)
#pragma unroll
                    for (int r = 0; r < 4; ++r) {
                        sm[nt] += xi[nt][r];
                        mxv[nt] = fmaxf(mxv[nt], xi[nt][r]);
                    }
            } else {
#pragma unroll
                for (int nt = 0; nt < 4; ++nt)
#pragma unroll
                    for (int r = 0; r < 4; ++r) {
                        bool act = (4 * q + r) < nb;
                        sm[nt] += act ? xi[nt][r] : 0.f;
                        mxv[nt] = fmaxf(mxv[nt], act ? xi[nt][r] : -INFINITY);
                    }
            }
            if (fin == end_cur) { flushseg(cur); ++cur; end_cur = st2; }
        } else {
            const int B = end_cur - base;   // 1..nb-1
#pragma unroll
            for (int nt = 0; nt < 4; ++nt)
#pragma unroll
                for (int r = 0; r < 4; ++r) {
                    bool act = (4 * q + r) < B;
                    sm[nt] += act ? xi[nt][r] : 0.f;
                    mxv[nt] = fmaxf(mxv[nt], act ? xi[nt][r] : -INFINITY);
                }
            flushseg(cur); ++cur;
#pragma unroll
            for (int nt = 0; nt < 4; ++nt)
#pragma unroll
                for (int r = 0; r < 4; ++r) {
                    int pt = 4 * q + r;
                    bool act = (pt >= B) && (pt < nb);
                    sm[nt] += act ? xi[nt][r] : 0.f;
                    mxv[nt] = fmaxf(mxv[nt], act ? xi[nt][r] : -INFINITY);
                }
            end_cur = st2;
        }
    }
}

extern "C" void kernel_launch(void* const* d_in, const int* in_sizes, int n_in,
                              void* d_out, int out_size, void* d_ws, size_t ws_size,
                              hipStream_t stream) {
    const float* inp   = (const float*)d_in[0];
    const int*   unq   = (const int*)d_in[1];
    const float* W     = (const float*)d_in[2];
    const float* gamma = (const float*)d_in[3];
    const float* beta  = (const float*)d_in[4];
    const float* dw1   = (const float*)d_in[5];
    const float* pw1   = (const float*)d_in[6];
    const float* dw2   = (const float*)d_in[7];
    const float* pw2   = (const float*)d_in[8];
    float* out = (float*)d_out;
    float* ws  = (float*)d_ws;
    int* starts = (int*)ws + 1024;

    hipMemsetAsync(ws, 0, 384 * sizeof(float), stream);   // zero accumulators

    k_moments <<<1024, 256, 0, stream>>>(inp, unq, ws, starts);
    k_gstats  <<<1024, 256, 0, stream>>>(inp, W, gamma, beta, ws);
    k_prep    <<<1,    64,  0, stream>>>(W, gamma, beta, dw1, pw1, dw2, pw2, ws);
    k_main    <<<7500, 128, 0, stream>>>(inp, ws, starts, out);
}